// Round 12
// baseline (215.466 us; speedup 1.0000x reference)
//
#include <hip/hip_runtime.h>
#include <hip/hip_fp16.h>
#include <cstdint>
#include <cstddef>

#define NEG_SLOPE 0.2f
#define LN_EPS 1e-5f

constexpr int BS = 256;
constexpr int EPT = 8;       // edges per pass-1 thread (2048/block)
constexpr int SUBCAP = 96;   // per-(bucket,block) edge capacity: mean 42, +8 sigma; mult of 8
constexpr int STRIDE = 96;   // slots per dst node; slot 0 = self-loop. Poisson(12) -> max ~40.

typedef _Float16 f16x8 __attribute__((ext_vector_type(8)));
typedef _Float16 f16x4 __attribute__((ext_vector_type(4)));
typedef float f32x4 __attribute__((ext_vector_type(4)));

// 8-deep gather of one 64-channel SLICE (8B per lane): ids/weights already in
// registers -> no load-chain; 8 half-row gathers in flight, then 32 fmas.
// byteoff = slice*128 + l4*8. Masked edges id=0,w=0 (row 0 L2-hot; adds 0).
__device__ __forceinline__ void agg_slice8(
    const char* hbB, int idk, float wk, int qbase, int hoff, int byteoff, float acc[4])
{
    f16x4 hv[8];
    #pragma unroll
    for (int i = 0; i < 8; ++i) {
        int si = __shfl(idk, qbase + hoff + i);
        hv[i] = *(const f16x4*)(hbB + ((size_t)si << 8) + byteoff);
    }
    #pragma unroll
    for (int i = 0; i < 8; ++i) {
        float wi = __shfl(wk, qbase + hoff + i);
        #pragma unroll
        for (int c = 0; c < 4; ++c)
            acc[c] = fmaf(wi, (float)hv[i][c], acc[c]);
    }
}

// ==================== K0: pass-1 bucketize (NO global atomics) + weight transposes ====
__global__ __launch_bounds__(256) void k_init(
    const int* __restrict__ esrc, const int* __restrict__ edst,
    unsigned int* __restrict__ gb, int* __restrict__ bcnt,
    const float* __restrict__ W1, const float* __restrict__ W2,
    _Float16* __restrict__ Wt1, _Float16* __restrict__ Wt2,
    int e, int nb, int nblk)
{
    int b = blockIdx.x;
    if (b < nblk) {
        __shared__ int lcnt[64];
        int tid = threadIdx.x;
        if (tid < 64) lcnt[tid] = 0;
        __syncthreads();
        int base = b * (BS * EPT) + tid;
        int sv[EPT], dl[EPT], bk[EPT], lp[EPT];
        #pragma unroll
        for (int u = 0; u < EPT; ++u) {
            int i = base + u * BS;
            bool ok = i < e;
            int ii = ok ? i : 0;
            sv[u] = esrc[ii];
            int d = edst[ii];
            dl[u] = d & 1023;
            bk[u] = ok ? (d >> 10) : -1;
        }
        #pragma unroll
        for (int u = 0; u < EPT; ++u)
            lp[u] = (bk[u] >= 0) ? atomicAdd(&lcnt[bk[u]], 1) : SUBCAP;
        __syncthreads();
        if (tid < nb) bcnt[b * nb + tid] = lcnt[tid] < SUBCAP ? lcnt[tid] : SUBCAP;
        #pragma unroll
        for (int u = 0; u < EPT; ++u)
            if (bk[u] >= 0 && lp[u] < SUBCAP)
                gb[((size_t)bk[u] * nblk + b) * SUBCAP + lp[u]] =
                    ((unsigned)dl[u] << 16) | (unsigned)sv[u];
    } else {
        int idx = (b - nblk) * BS + threadIdx.x;
        if (idx < 128 * 160) {
            int nn = idx / 160, k = idx - nn * 160;
            Wt1[idx] = (_Float16)((k < 136) ? W1[(size_t)k * 128 + nn] : 0.f);
        } else if (idx < 128 * 160 + 128 * 128) {
            int j = idx - 128 * 160;
            int nn = j >> 7, k = j & 127;
            Wt2[j] = (_Float16)W2[(size_t)k * 128 + nn];
        }
    }
}

// ==================== K1: pass-2 CSR build (8-deep MLP batched) + gemm1 ====================
__global__ __launch_bounds__(256) void k_csr_gemm1(
    const unsigned int* __restrict__ gb, const int* __restrict__ bcnt,
    int* __restrict__ cnt, unsigned short* __restrict__ sn,
    const float* __restrict__ x, const int* __restrict__ cid,
    const float* __restrict__ emb,
    const _Float16* __restrict__ Wt1,
    const float* __restrict__ a_src, const float* __restrict__ a_dst,
    _Float16* __restrict__ hb, float* __restrict__ as_, float* __restrict__ ad_,
    int n, int nb, int nblk)
{
    __shared__ float red[2][16][2][2];   // [rowgrp][r15][colhalf][vs/vd]
    __shared__ int cl[1024];
    int b = blockIdx.x;

    if (b < nb) {
        int tid = threadIdx.x;
        #pragma unroll 4
        for (int i = tid; i < 1024; i += BS) cl[i] = 1;   // slot 0 = self-loop
        __syncthreads();
        for (int blk = tid; blk < nblk; blk += BS) {
            int c = bcnt[blk * nb + b];
            size_t gbase = ((size_t)b * nblk + blk) * SUBCAP;
            for (int j = 0; j < c; j += 8) {
                uint4 p0 = *(const uint4*)(gb + gbase + j);        // 8 edges in flight
                uint4 p1 = *(const uint4*)(gb + gbase + j + 4);
                unsigned pk[8] = {p0.x, p0.y, p0.z, p0.w, p1.x, p1.y, p1.z, p1.w};
                int slot[8];
                #pragma unroll
                for (int k = 0; k < 8; ++k)
                    slot[k] = (j + k < c) ? atomicAdd(&cl[pk[k] >> 16], 1) : STRIDE;
                #pragma unroll
                for (int k = 0; k < 8; ++k)
                    if (slot[k] < STRIDE)
                        sn[((size_t)(b * 1024 + (int)(pk[k] >> 16))) * STRIDE + slot[k]] =
                            (unsigned short)(pk[k] & 0xFFFFu);
            }
        }
        __syncthreads();
        for (int i = tid; i < 1024; i += BS) {
            int node = b * 1024 + i;
            if (node < n) {
                int c = cl[i];
                cnt[node] = c < STRIDE ? c : STRIDE;
                sn[(size_t)node * STRIDE] = (unsigned short)node;
            }
        }
        return;
    }

    // ---- gemm1 tile (unchanged)
    int idx = b - nb;
    int tid = threadIdx.x;
    int wave = tid >> 6, lane = tid & 63;
    int rg = wave >> 1, ch = wave & 1;
    int r15 = lane & 15, q = lane >> 4;
    int rowBase = idx * 32 + rg * 16;
    int colBase = ch * 64;
    int row = rowBase + r15;
    bool ok = row < n;
    int rl = ok ? row : n - 1;                 // clamped load row (no OOB reads)

    f32x4 acc[4] = {};
    const _Float16* Wp[4];
    #pragma unroll
    for (int s = 0; s < 4; ++s)
        Wp[s] = Wt1 + (size_t)(colBase + s * 16 + r15) * 160 + q * 8;
    const float* Xp = x + (size_t)rl * 128 + q * 8;

    #pragma unroll
    for (int k0 = 0; k0 < 128; k0 += 32) {
        f16x8 wv[4];
        #pragma unroll
        for (int s = 0; s < 4; ++s) wv[s] = *(const f16x8*)(Wp[s] + k0);
        float4 xlo = *(const float4*)(Xp + k0);
        float4 xhi = *(const float4*)(Xp + k0 + 4);
        f16x8 xv;
        xv[0] = (_Float16)xlo.x; xv[1] = (_Float16)xlo.y;
        xv[2] = (_Float16)xlo.z; xv[3] = (_Float16)xlo.w;
        xv[4] = (_Float16)xhi.x; xv[5] = (_Float16)xhi.y;
        xv[6] = (_Float16)xhi.z; xv[7] = (_Float16)xhi.w;
        #pragma unroll
        for (int s = 0; s < 4; ++s)
            acc[s] = __builtin_amdgcn_mfma_f32_16x16x32_f16(wv[s], xv, acc[s], 0, 0, 0);
    }
    {   // tail k0=128: k=128..135 are emb features (q==0 lanes); 136..159 zero (Wt1 padded)
        f16x8 wv[4];
        #pragma unroll
        for (int s = 0; s < 4; ++s) wv[s] = *(const f16x8*)(Wp[s] + 128);
        f16x8 xv;
        #pragma unroll
        for (int j = 0; j < 8; ++j) xv[j] = (_Float16)0.f;
        if (q == 0) {
            const float* er = emb + (size_t)cid[rl] * 8;
            float4 e0 = *(const float4*)er;
            float4 e1 = *(const float4*)(er + 4);
            xv[0] = (_Float16)e0.x; xv[1] = (_Float16)e0.y;
            xv[2] = (_Float16)e0.z; xv[3] = (_Float16)e0.w;
            xv[4] = (_Float16)e1.x; xv[5] = (_Float16)e1.y;
            xv[6] = (_Float16)e1.z; xv[7] = (_Float16)e1.w;
        }
        #pragma unroll
        for (int s = 0; s < 4; ++s)
            acc[s] = __builtin_amdgcn_mfma_f32_16x16x32_f16(wv[s], xv, acc[s], 0, 0, 0);
    }

    float vs = 0.f, vd = 0.f;
    #pragma unroll
    for (int s = 0; s < 4; ++s) {
        float4 as4 = *(const float4*)&a_src[colBase + s * 16 + q * 4];
        float4 ad4 = *(const float4*)&a_dst[colBase + s * 16 + q * 4];
        f32x4 d = acc[s];
        vs += d[0]*as4.x + d[1]*as4.y + d[2]*as4.z + d[3]*as4.w;
        vd += d[0]*ad4.x + d[1]*ad4.y + d[2]*ad4.z + d[3]*ad4.w;
        if (ok) {
            ushort4 u;
            u.x = __half_as_ushort(__float2half_rn(d[0]));
            u.y = __half_as_ushort(__float2half_rn(d[1]));
            u.z = __half_as_ushort(__float2half_rn(d[2]));
            u.w = __half_as_ushort(__float2half_rn(d[3]));
            *(ushort4*)&hb[(size_t)row * 128 + colBase + s * 16 + q * 4] = u;
        }
    }
    vs += __shfl_xor(vs, 16); vs += __shfl_xor(vs, 32);
    vd += __shfl_xor(vd, 16); vd += __shfl_xor(vd, 32);
    if (q == 0) { red[rg][r15][ch][0] = vs; red[rg][r15][ch][1] = vd; }
    __syncthreads();
    if (ch == 0 && q == 0 && ok) {
        as_[row] = red[rg][r15][0][0] + red[rg][r15][1][0];
        ad_[row] = red[rg][r15][0][1] + red[rg][r15][1][1];
    }
}

// ==================== K2: agg layer1 (channel-sliced 2-phase) + LN/ELU + gemm2 ====================
// R11 post-mortem: K2 pinned at 52us with FETCH=70MB across 3 schedules ->
// L2-miss service wall (12.8MB working set vs 4MB XCD L2, 58% hit). Fix the
// FOOTPRINT: phase A gathers channels 0..63 of all nodes (hot set = rows'
// first 128B = 6.4MB), block barrier (chip-wide phase alignment), phase B
// gathers channels 64..127. Weights computed once, carried in registers.
// Pure per-channel reordering -> bit-identical output.
__global__ __launch_bounds__(512, 4) void k_agg1_gemm2(
    const _Float16* __restrict__ h1, const unsigned short* __restrict__ sn,
    const int* __restrict__ cnt, const float* __restrict__ as1,
    const float* __restrict__ ad1, const float* __restrict__ b1,
    const float* __restrict__ lng, const float* __restrict__ lnb,
    const _Float16* __restrict__ Wt2,
    const float* __restrict__ a_src2, const float* __restrict__ a_dst2,
    _Float16* __restrict__ h2, float* __restrict__ as2, float* __restrict__ ad2,
    int nn)
{
    __shared__ _Float16 yt[32][144];
    __shared__ float red[2][16][4][2];
    int t = blockIdx.x;
    int tid = threadIdx.x;
    int wave = tid >> 6, lane = tid & 63;
    int l4 = lane & 15, q = lane >> 4;
    int qg = wave * 4 + q;                     // 0..31: this quarter's node slot in the tile
    int node = t * 32 + qg;
    bool valid = node < nn;
    const char* hbB = (const char*)h1;
    int qbase = lane & 48;

    int len = 0; float adv = 0.f;
    if (valid) {
        len = cnt[node];
        len = len < STRIDE ? len : STRIDE;
        adv = ad1[node];
    }
    int start = valid ? node * STRIDE : 0;

    // preload all <=48 edge ids + weights ONCE (masked -> id 0, w 0)
    int id0 = sn[start + l4], id1 = sn[start + 16 + l4], id2 = sn[start + 32 + l4];
    id0 = (l4      < len) ? id0 : 0;
    id1 = (l4 + 16 < len) ? id1 : 0;
    id2 = (l4 + 32 < len) ? id2 : 0;
    float t0 = as1[id0] + adv; t0 = t0 > 0.f ? t0 : NEG_SLOPE * t0;
    float t1 = as1[id1] + adv; t1 = t1 > 0.f ? t1 : NEG_SLOPE * t1;
    float t2 = as1[id2] + adv; t2 = t2 > 0.f ? t2 : NEG_SLOPE * t2;
    float w0 = (l4      < len) ? __expf(fminf(t0, 70.f)) : 0.f;
    float w1 = (l4 + 16 < len) ? __expf(fminf(t1, 70.f)) : 0.f;
    float w2 = (l4 + 32 < len) ? __expf(fminf(t2, 70.f)) : 0.f;
    float wsum = w0 + w1 + w2;

    int offA = l4 * 8;            // slice A: channels 4*l4 .. 4*l4+3
    int offB = 128 + l4 * 8;      // slice B: channels 64+4*l4 .. +3
    float accA[4] = {0.f, 0.f, 0.f, 0.f};
    float accB[4] = {0.f, 0.f, 0.f, 0.f};

    // ---- PHASE A: channels 0..63 of all nodes
    agg_slice8(hbB, id0, w0, qbase, 0, offA, accA);
    agg_slice8(hbB, id0, w0, qbase, 8, offA, accA);
    if (len > 16) {
        agg_slice8(hbB, id1, w1, qbase, 0, offA, accA);
        agg_slice8(hbB, id1, w1, qbase, 8, offA, accA);
    }
    if (len > 32) {
        agg_slice8(hbB, id2, w2, qbase, 0, offA, accA);
        agg_slice8(hbB, id2, w2, qbase, 8, offA, accA);
    }
    for (int c = 48; c < len; c += 16) {       // correctness guard; never runs for this data
        int idk = sn[start + c + l4];
        bool a = (c + l4 < len);
        idk = a ? idk : 0;
        float tt = as1[idk] + adv; tt = tt > 0.f ? tt : NEG_SLOPE * tt;
        float wk = a ? __expf(fminf(tt, 70.f)) : 0.f;
        wsum += wk;
        agg_slice8(hbB, idk, wk, qbase, 0, offA, accA);
        agg_slice8(hbB, idk, wk, qbase, 8, offA, accA);
    }
    __syncthreads();                            // chip-wide slice alignment
    // ---- PHASE B: channels 64..127
    agg_slice8(hbB, id0, w0, qbase, 0, offB, accB);
    agg_slice8(hbB, id0, w0, qbase, 8, offB, accB);
    if (len > 16) {
        agg_slice8(hbB, id1, w1, qbase, 0, offB, accB);
        agg_slice8(hbB, id1, w1, qbase, 8, offB, accB);
    }
    if (len > 32) {
        agg_slice8(hbB, id2, w2, qbase, 0, offB, accB);
        agg_slice8(hbB, id2, w2, qbase, 8, offB, accB);
    }
    for (int c = 48; c < len; c += 16) {       // correctness guard; never runs for this data
        int idk = sn[start + c + l4];
        bool a = (c + l4 < len);
        idk = a ? idk : 0;
        float tt = as1[idk] + adv; tt = tt > 0.f ? tt : NEG_SLOPE * tt;
        float wk = a ? __expf(fminf(tt, 70.f)) : 0.f;
        agg_slice8(hbB, idk, wk, qbase, 0, offB, accB);
        agg_slice8(hbB, idk, wk, qbase, 8, offB, accB);
    }

    float dsum = wsum;
    dsum += __shfl_xor(dsum, 1); dsum += __shfl_xor(dsum, 2);
    dsum += __shfl_xor(dsum, 4); dsum += __shfl_xor(dsum, 8);

    if (valid) {
        float inv = 1.f / dsum;
        float4 bA = *(const float4*)&b1[l4 * 4];
        float4 bB = *(const float4*)&b1[64 + l4 * 4];
        float vv[8];
        vv[0] = accA[0] * inv + bA.x; vv[1] = accA[1] * inv + bA.y;
        vv[2] = accA[2] * inv + bA.z; vv[3] = accA[3] * inv + bA.w;
        vv[4] = accB[0] * inv + bB.x; vv[5] = accB[1] * inv + bB.y;
        vv[6] = accB[2] * inv + bB.z; vv[7] = accB[3] * inv + bB.w;

        // LayerNorm across the quarter's 16 lanes (each lane holds 8 of 128 ch)
        float s1 = 0.f, s2 = 0.f;
        #pragma unroll
        for (int c = 0; c < 8; ++c) { s1 += vv[c]; s2 += vv[c] * vv[c]; }
        #pragma unroll
        for (int o = 1; o < 16; o <<= 1) {
            s1 += __shfl_xor(s1, o);
            s2 += __shfl_xor(s2, o);
        }
        float mean = s1 * (1.f / 128.f);
        float var  = s2 * (1.f / 128.f) - mean * mean;
        float r = rsqrtf(var + LN_EPS);
        float4 gA = *(const float4*)&lng[l4 * 4];
        float4 gB = *(const float4*)&lng[64 + l4 * 4];
        float4 pA = *(const float4*)&lnb[l4 * 4];
        float4 pB = *(const float4*)&lnb[64 + l4 * 4];
        float gg[8] = {gA.x, gA.y, gA.z, gA.w, gB.x, gB.y, gB.z, gB.w};
        float pp[8] = {pA.x, pA.y, pA.z, pA.w, pB.x, pB.y, pB.z, pB.w};
        f16x4 oA, oB;
        #pragma unroll
        for (int c = 0; c < 8; ++c) {
            float u = (vv[c] - mean) * r * gg[c] + pp[c];
            u = u > 0.f ? u : __expf(u) - 1.f;   // ELU
            if (c < 4) oA[c] = (_Float16)u; else oB[c - 4] = (_Float16)u;
        }
        *(f16x4*)&yt[qg][l4 * 4]      = oA;
        *(f16x4*)&yt[qg][64 + l4 * 4] = oB;
    } else {
        f16x4 z;
        #pragma unroll
        for (int c = 0; c < 4; ++c) z[c] = (_Float16)0.f;
        *(f16x4*)&yt[qg][l4 * 4]      = z;
        *(f16x4*)&yt[qg][64 + l4 * 4] = z;
    }
    __syncthreads();

    // ---- gemm2 (K=128) from the LDS tile: 8 waves = 2 rowgroups x 4 col-chunks
    int rg = wave >> 2, cc = wave & 3;
    int r15 = l4;
    int row = t * 32 + rg * 16 + r15;
    bool ok = row < nn;

    f32x4 acc2[2] = {};
    const _Float16* Wp[2];
    #pragma unroll
    for (int s = 0; s < 2; ++s)
        Wp[s] = Wt2 + (size_t)(cc * 32 + s * 16 + r15) * 128 + q * 8;
    const _Float16* Yp = &yt[rg * 16 + r15][q * 8];

    #pragma unroll
    for (int k0 = 0; k0 < 128; k0 += 32) {
        f16x8 wv[2];
        #pragma unroll
        for (int s = 0; s < 2; ++s) wv[s] = *(const f16x8*)(Wp[s] + k0);
        f16x8 xv = *(const f16x8*)(Yp + k0);
        #pragma unroll
        for (int s = 0; s < 2; ++s)
            acc2[s] = __builtin_amdgcn_mfma_f32_16x16x32_f16(wv[s], xv, acc2[s], 0, 0, 0);
    }

    float vs = 0.f, vd = 0.f;
    #pragma unroll
    for (int s = 0; s < 2; ++s) {
        float4 as4 = *(const float4*)&a_src2[cc * 32 + s * 16 + q * 4];
        float4 ad4 = *(const float4*)&a_dst2[cc * 32 + s * 16 + q * 4];
        f32x4 d = acc2[s];
        vs += d[0]*as4.x + d[1]*as4.y + d[2]*as4.z + d[3]*as4.w;
        vd += d[0]*ad4.x + d[1]*ad4.y + d[2]*ad4.z + d[3]*ad4.w;
        if (ok) {
            ushort4 u;
            u.x = __half_as_ushort(__float2half_rn(d[0]));
            u.y = __half_as_ushort(__float2half_rn(d[1]));
            u.z = __half_as_ushort(__float2half_rn(d[2]));
            u.w = __half_as_ushort(__float2half_rn(d[3]));
            *(ushort4*)&h2[(size_t)row * 128 + cc * 32 + s * 16 + q * 4] = u;
        }
    }
    vs += __shfl_xor(vs, 16); vs += __shfl_xor(vs, 32);
    vd += __shfl_xor(vd, 16); vd += __shfl_xor(vd, 32);
    if (q == 0) { red[rg][r15][cc][0] = vs; red[rg][r15][cc][1] = vd; }
    __syncthreads();
    if (cc == 0 && q == 0 && ok) {
        as2[row] = red[rg][r15][0][0] + red[rg][r15][1][0]
                 + red[rg][r15][2][0] + red[rg][r15][3][0];
        ad2[row] = red[rg][r15][0][1] + red[rg][r15][1][1]
                 + red[rg][r15][2][1] + red[rg][r15][3][1];
    }
}

// ==================== K3: agg layer2 (channel-sliced 2-phase, fp32 out) ====================
__global__ __launch_bounds__(256, 4) void k_agg2(
    const _Float16* __restrict__ hb, const unsigned short* __restrict__ sn,
    const int* __restrict__ cnt, const float* __restrict__ as_,
    const float* __restrict__ ad_, const float* __restrict__ bias,
    float* __restrict__ out, int n_nodes)
{
    int tid = threadIdx.x;
    int wave = tid >> 6, lane = tid & 63;
    int l4 = lane & 15, q = lane >> 4;
    int node = blockIdx.x * 16 + wave * 4 + q;
    bool valid = node < n_nodes;
    int len = 0; float adv = 0.f;
    if (valid) {
        len = cnt[node];
        len = len < STRIDE ? len : STRIDE;
        adv = ad_[node];
    }
    int start = valid ? node * STRIDE : 0;
    int qbase = lane & 48;
    const char* hbB = (const char*)hb;

    int id0 = sn[start + l4], id1 = sn[start + 16 + l4], id2 = sn[start + 32 + l4];
    id0 = (l4      < len) ? id0 : 0;
    id1 = (l4 + 16 < len) ? id1 : 0;
    id2 = (l4 + 32 < len) ? id2 : 0;
    float t0 = as_[id0] + adv; t0 = t0 > 0.f ? t0 : NEG_SLOPE * t0;
    float t1 = as_[id1] + adv; t1 = t1 > 0.f ? t1 : NEG_SLOPE * t1;
    float t2 = as_[id2] + adv; t2 = t2 > 0.f ? t2 : NEG_SLOPE * t2;
    float w0 = (l4      < len) ? __expf(fminf(t0, 70.f)) : 0.f;
    float w1 = (l4 + 16 < len) ? __expf(fminf(t1, 70.f)) : 0.f;
    float w2 = (l4 + 32 < len) ? __expf(fminf(t2, 70.f)) : 0.f;
    float wsum = w0 + w1 + w2;

    int offA = l4 * 8;
    int offB = 128 + l4 * 8;
    float accA[4] = {0.f, 0.f, 0.f, 0.f};
    float accB[4] = {0.f, 0.f, 0.f, 0.f};

    // ---- PHASE A: channels 0..63
    agg_slice8(hbB, id0, w0, qbase, 0, offA, accA);
    agg_slice8(hbB, id0, w0, qbase, 8, offA, accA);
    if (len > 16) {
        agg_slice8(hbB, id1, w1, qbase, 0, offA, accA);
        agg_slice8(hbB, id1, w1, qbase, 8, offA, accA);
    }
    if (len > 32) {
        agg_slice8(hbB, id2, w2, qbase, 0, offA, accA);
        agg_slice8(hbB, id2, w2, qbase, 8, offA, accA);
    }
    for (int c = 48; c < len; c += 16) {       // correctness guard; never runs for this data
        int idk = sn[start + c + l4];
        bool a = (c + l4 < len);
        idk = a ? idk : 0;
        float tt = as_[idk] + adv; tt = tt > 0.f ? tt : NEG_SLOPE * tt;
        float wk = a ? __expf(fminf(tt, 70.f)) : 0.f;
        wsum += wk;
        agg_slice8(hbB, idk, wk, qbase, 0, offA, accA);
        agg_slice8(hbB, idk, wk, qbase, 8, offA, accA);
    }
    __syncthreads();                            // chip-wide slice alignment
    // ---- PHASE B: channels 64..127
    agg_slice8(hbB, id0, w0, qbase, 0, offB, accB);
    agg_slice8(hbB, id0, w0, qbase, 8, offB, accB);
    if (len > 16) {
        agg_slice8(hbB, id1, w1, qbase, 0, offB, accB);
        agg_slice8(hbB, id1, w1, qbase, 8, offB, accB);
    }
    if (len > 32) {
        agg_slice8(hbB, id2, w2, qbase, 0, offB, accB);
        agg_slice8(hbB, id2, w2, qbase, 8, offB, accB);
    }
    for (int c = 48; c < len; c += 16) {       // correctness guard; never runs for this data
        int idk = sn[start + c + l4];
        bool a = (c + l4 < len);
        idk = a ? idk : 0;
        float tt = as_[idk] + adv; tt = tt > 0.f ? tt : NEG_SLOPE * tt;
        float wk = a ? __expf(fminf(tt, 70.f)) : 0.f;
        agg_slice8(hbB, idk, wk, qbase, 0, offB, accB);
        agg_slice8(hbB, idk, wk, qbase, 8, offB, accB);
    }

    float dsum = wsum;
    dsum += __shfl_xor(dsum, 1); dsum += __shfl_xor(dsum, 2);
    dsum += __shfl_xor(dsum, 4); dsum += __shfl_xor(dsum, 8);

    if (valid) {
        float inv = 1.f / dsum;
        float4 bA = *(const float4*)&bias[l4 * 4];
        float4 bB = *(const float4*)&bias[64 + l4 * 4];
        float4 oA = make_float4(accA[0]*inv + bA.x, accA[1]*inv + bA.y,
                                accA[2]*inv + bA.z, accA[3]*inv + bA.w);
        float4 oB = make_float4(accB[0]*inv + bB.x, accB[1]*inv + bB.y,
                                accB[2]*inv + bB.z, accB[3]*inv + bB.w);
        *(float4*)(out + (size_t)node * 128 + l4 * 4)      = oA;
        *(float4*)(out + (size_t)node * 128 + 64 + l4 * 4) = oB;
    }
}

// ============================ launch ============================

extern "C" void kernel_launch(void* const* d_in, const int* in_sizes, int n_in,
                              void* d_out, int out_size, void* d_ws, size_t ws_size,
                              hipStream_t stream) {
    const float* x_base   = (const float*)d_in[0];
    const int*   cell_ids = (const int*)d_in[1];
    const int*   eidx     = (const int*)d_in[2];
    const float* cell_emb = (const float*)d_in[3];
    const float* W1     = (const float*)d_in[4];
    const float* a_src1 = (const float*)d_in[5];
    const float* a_dst1 = (const float*)d_in[6];
    const float* b1     = (const float*)d_in[7];
    const float* ln_g   = (const float*)d_in[8];
    const float* ln_b   = (const float*)d_in[9];
    const float* W2     = (const float*)d_in[10];
    const float* a_src2 = (const float*)d_in[11];
    const float* a_dst2 = (const float*)d_in[12];
    const float* b2     = (const float*)d_in[13];

    const int N = in_sizes[0] / 128;
    const int E = in_sizes[2] / 2;

    const int* esrc = eidx;
    const int* edst = eidx + E;

    const int NB   = (N + 1023) >> 10;               // dst-range buckets (1024 nodes each)
    const int NBLK = (E + BS * EPT - 1) / (BS * EPT); // pass-1 blocks (2048 edges each)

    auto align = [](size_t v) { return (v + 255) & ~(size_t)255; };
    char* p = (char*)d_ws;
    int*   cnt    = (int*)p;   p += align((size_t)N * 4);
    unsigned short* sn = (unsigned short*)p; p += align((size_t)N * STRIDE * 2 + 64);
    unsigned int* gb = (unsigned int*)p; p += align((size_t)NB * NBLK * SUBCAP * 4);
    int*   bcnt   = (int*)p;   p += align((size_t)NBLK * NB * 4);
    _Float16* h1  = (_Float16*)p; p += align((size_t)N * 128 * 2);
    _Float16* h2  = (_Float16*)p; p += align((size_t)N * 128 * 2);
    _Float16* Wt1 = (_Float16*)p; p += align((size_t)128 * 160 * 2);
    _Float16* Wt2 = (_Float16*)p; p += align((size_t)128 * 128 * 2);
    float* as1    = (float*)p; p += align((size_t)N * 4);
    float* ad1    = (float*)p; p += align((size_t)N * 4);
    float* as2    = (float*)p; p += align((size_t)N * 4);
    float* ad2    = (float*)p; p += align((size_t)N * 4);
    (void)ws_size; (void)n_in; (void)out_size;

    const int nbG = (N + 31) / 32;                     // 32-row gemm tiles
    const int wblocks = (128 * 160 + 128 * 128 + BS - 1) / BS;

    k_init<<<NBLK + wblocks, BS, 0, stream>>>(
        esrc, edst, gb, bcnt, W1, W2, Wt1, Wt2, E, NB, NBLK);
    k_csr_gemm1<<<NB + nbG, BS, 0, stream>>>(
        gb, bcnt, cnt, sn, x_base, cell_ids, cell_emb, Wt1,
        a_src1, a_dst1, h1, as1, ad1, N, NB, NBLK);
    k_agg1_gemm2<<<nbG, 512, 0, stream>>>(
        h1, sn, cnt, as1, ad1, b1, ln_g, ln_b, Wt2,
        a_src2, a_dst2, h2, as2, ad2, N);
    k_agg2<<<(N + 15) / 16, BS, 0, stream>>>(
        h2, sn, cnt, as2, ad2, b2, (float*)d_out, N);
}

// Round 13
// 204.208 us; speedup vs baseline: 1.0551x; 1.0551x over previous
//
#include <hip/hip_runtime.h>
#include <hip/hip_fp16.h>
#include <cstdint>
#include <cstddef>

#define NEG_SLOPE 0.2f
#define LN_EPS 1e-5f

constexpr int BS = 256;
constexpr int EPT = 8;       // edges per pass-1 thread (2048/block)
constexpr int SUBCAP = 96;   // per-(block,bucket) edge capacity: mean 42, +8 sigma; mult of 8
constexpr int STRIDE = 96;   // slots per dst node; slot 0 = self-loop. Poisson(12) -> max ~40.

typedef _Float16 f16x8 __attribute__((ext_vector_type(8)));
typedef float f32x4 __attribute__((ext_vector_type(4)));

// 8-deep gather half-chunk: ids/weights already in registers -> no load-chain
// between chunks; 8 row gathers in flight, then 64 fmas. Masked edges id=0,w=0.
__device__ __forceinline__ void agg_half8(
    const char* hbB, int idk, float wk, int qbase, int hoff, int l4, float acc[8])
{
    f16x8 hv[8];
    #pragma unroll
    for (int i = 0; i < 8; ++i) {
        int si = __shfl(idk, qbase + hoff + i);
        hv[i] = *(const f16x8*)(hbB + ((size_t)si << 8) + l4 * 16);
    }
    #pragma unroll
    for (int i = 0; i < 8; ++i) {
        float wi = __shfl(wk, qbase + hoff + i);
        #pragma unroll
        for (int c = 0; c < 8; ++c)
            acc[c] = fmaf(wi, (float)hv[i][c], acc[c]);
    }
}

// ==================== K0: pass-1 bucketize (NO global atomics) + weight transposes ====
// gb layout is now (block, bucket): each block writes a contiguous 18.8KB
// window -> L2 write-combines instead of 4B-grain RMW scatter over 18MB
// (R1 measured that scatter pattern at ~2.2x write amplification).
__global__ __launch_bounds__(256) void k_init(
    const int* __restrict__ esrc, const int* __restrict__ edst,
    unsigned int* __restrict__ gb, int* __restrict__ bcnt,
    const float* __restrict__ W1, const float* __restrict__ W2,
    _Float16* __restrict__ Wt1, _Float16* __restrict__ Wt2,
    int e, int nb, int nblk)
{
    int b = blockIdx.x;
    if (b < nblk) {
        __shared__ int lcnt[64];
        int tid = threadIdx.x;
        if (tid < 64) lcnt[tid] = 0;
        __syncthreads();
        int base = b * (BS * EPT) + tid;
        int sv[EPT], dl[EPT], bk[EPT], lp[EPT];
        #pragma unroll
        for (int u = 0; u < EPT; ++u) {
            int i = base + u * BS;
            bool ok = i < e;
            int ii = ok ? i : 0;
            sv[u] = esrc[ii];
            int d = edst[ii];
            dl[u] = d & 1023;
            bk[u] = ok ? (d >> 10) : -1;
        }
        #pragma unroll
        for (int u = 0; u < EPT; ++u)
            lp[u] = (bk[u] >= 0) ? atomicAdd(&lcnt[bk[u]], 1) : SUBCAP;
        __syncthreads();
        if (tid < nb) bcnt[b * nb + tid] = lcnt[tid] < SUBCAP ? lcnt[tid] : SUBCAP;
        #pragma unroll
        for (int u = 0; u < EPT; ++u)
            if (bk[u] >= 0 && lp[u] < SUBCAP)
                gb[((size_t)b * nb + bk[u]) * SUBCAP + lp[u]] =
                    ((unsigned)dl[u] << 16) | (unsigned)sv[u];
    } else {
        int idx = (b - nblk) * BS + threadIdx.x;
        if (idx < 128 * 160) {
            int nn = idx / 160, k = idx - nn * 160;
            Wt1[idx] = (_Float16)((k < 136) ? W1[(size_t)k * 128 + nn] : 0.f);
        } else if (idx < 128 * 160 + 128 * 128) {
            int j = idx - 128 * 160;
            int nn = j >> 7, k = j & 127;
            Wt2[j] = (_Float16)W2[(size_t)k * 128 + nn];
        }
    }
}

// ==================== K1: pass-2 CSR build (8-deep MLP batched) + gemm1 ====================
__global__ __launch_bounds__(256) void k_csr_gemm1(
    const unsigned int* __restrict__ gb, const int* __restrict__ bcnt,
    int* __restrict__ cnt, unsigned short* __restrict__ sn,
    const float* __restrict__ x, const int* __restrict__ cid,
    const float* __restrict__ emb,
    const _Float16* __restrict__ Wt1,
    const float* __restrict__ a_src, const float* __restrict__ a_dst,
    _Float16* __restrict__ hb, float* __restrict__ as_, float* __restrict__ ad_,
    int n, int nb, int nblk)
{
    __shared__ float red[2][16][2][2];   // [rowgrp][r15][colhalf][vs/vd]
    __shared__ int cl[1024];
    int b = blockIdx.x;

    if (b < nb) {
        int tid = threadIdx.x;
        #pragma unroll 4
        for (int i = tid; i < 1024; i += BS) cl[i] = 1;   // slot 0 = self-loop
        __syncthreads();
        for (int blk = tid; blk < nblk; blk += BS) {
            int c = bcnt[blk * nb + b];
            size_t gbase = ((size_t)blk * nb + b) * SUBCAP;
            for (int j = 0; j < c; j += 8) {
                uint4 p0 = *(const uint4*)(gb + gbase + j);        // 8 edges in flight
                uint4 p1 = *(const uint4*)(gb + gbase + j + 4);
                unsigned pk[8] = {p0.x, p0.y, p0.z, p0.w, p1.x, p1.y, p1.z, p1.w};
                int slot[8];
                #pragma unroll
                for (int k = 0; k < 8; ++k)
                    slot[k] = (j + k < c) ? atomicAdd(&cl[pk[k] >> 16], 1) : STRIDE;
                #pragma unroll
                for (int k = 0; k < 8; ++k)
                    if (slot[k] < STRIDE)
                        sn[((size_t)(b * 1024 + (int)(pk[k] >> 16))) * STRIDE + slot[k]] =
                            (unsigned short)(pk[k] & 0xFFFFu);
            }
        }
        __syncthreads();
        for (int i = tid; i < 1024; i += BS) {
            int node = b * 1024 + i;
            if (node < n) {
                int c = cl[i];
                cnt[node] = c < STRIDE ? c : STRIDE;
                sn[(size_t)node * STRIDE] = (unsigned short)node;
            }
        }
        return;
    }

    // ---- gemm1 tile (unchanged)
    int idx = b - nb;
    int tid = threadIdx.x;
    int wave = tid >> 6, lane = tid & 63;
    int rg = wave >> 1, ch = wave & 1;
    int r15 = lane & 15, q = lane >> 4;
    int rowBase = idx * 32 + rg * 16;
    int colBase = ch * 64;
    int row = rowBase + r15;
    bool ok = row < n;
    int rl = ok ? row : n - 1;                 // clamped load row (no OOB reads)

    f32x4 acc[4] = {};
    const _Float16* Wp[4];
    #pragma unroll
    for (int s = 0; s < 4; ++s)
        Wp[s] = Wt1 + (size_t)(colBase + s * 16 + r15) * 160 + q * 8;
    const float* Xp = x + (size_t)rl * 128 + q * 8;

    #pragma unroll
    for (int k0 = 0; k0 < 128; k0 += 32) {
        f16x8 wv[4];
        #pragma unroll
        for (int s = 0; s < 4; ++s) wv[s] = *(const f16x8*)(Wp[s] + k0);
        float4 xlo = *(const float4*)(Xp + k0);
        float4 xhi = *(const float4*)(Xp + k0 + 4);
        f16x8 xv;
        xv[0] = (_Float16)xlo.x; xv[1] = (_Float16)xlo.y;
        xv[2] = (_Float16)xlo.z; xv[3] = (_Float16)xlo.w;
        xv[4] = (_Float16)xhi.x; xv[5] = (_Float16)xhi.y;
        xv[6] = (_Float16)xhi.z; xv[7] = (_Float16)xhi.w;
        #pragma unroll
        for (int s = 0; s < 4; ++s)
            acc[s] = __builtin_amdgcn_mfma_f32_16x16x32_f16(wv[s], xv, acc[s], 0, 0, 0);
    }
    {   // tail k0=128: k=128..135 are emb features (q==0 lanes); 136..159 zero (Wt1 padded)
        f16x8 wv[4];
        #pragma unroll
        for (int s = 0; s < 4; ++s) wv[s] = *(const f16x8*)(Wp[s] + 128);
        f16x8 xv;
        #pragma unroll
        for (int j = 0; j < 8; ++j) xv[j] = (_Float16)0.f;
        if (q == 0) {
            const float* er = emb + (size_t)cid[rl] * 8;
            float4 e0 = *(const float4*)er;
            float4 e1 = *(const float4*)(er + 4);
            xv[0] = (_Float16)e0.x; xv[1] = (_Float16)e0.y;
            xv[2] = (_Float16)e0.z; xv[3] = (_Float16)e0.w;
            xv[4] = (_Float16)e1.x; xv[5] = (_Float16)e1.y;
            xv[6] = (_Float16)e1.z; xv[7] = (_Float16)e1.w;
        }
        #pragma unroll
        for (int s = 0; s < 4; ++s)
            acc[s] = __builtin_amdgcn_mfma_f32_16x16x32_f16(wv[s], xv, acc[s], 0, 0, 0);
    }

    float vs = 0.f, vd = 0.f;
    #pragma unroll
    for (int s = 0; s < 4; ++s) {
        float4 as4 = *(const float4*)&a_src[colBase + s * 16 + q * 4];
        float4 ad4 = *(const float4*)&a_dst[colBase + s * 16 + q * 4];
        f32x4 d = acc[s];
        vs += d[0]*as4.x + d[1]*as4.y + d[2]*as4.z + d[3]*as4.w;
        vd += d[0]*ad4.x + d[1]*ad4.y + d[2]*ad4.z + d[3]*ad4.w;
        if (ok) {
            ushort4 u;
            u.x = __half_as_ushort(__float2half_rn(d[0]));
            u.y = __half_as_ushort(__float2half_rn(d[1]));
            u.z = __half_as_ushort(__float2half_rn(d[2]));
            u.w = __half_as_ushort(__float2half_rn(d[3]));
            *(ushort4*)&hb[(size_t)row * 128 + colBase + s * 16 + q * 4] = u;
        }
    }
    vs += __shfl_xor(vs, 16); vs += __shfl_xor(vs, 32);
    vd += __shfl_xor(vd, 16); vd += __shfl_xor(vd, 32);
    if (q == 0) { red[rg][r15][ch][0] = vs; red[rg][r15][ch][1] = vd; }
    __syncthreads();
    if (ch == 0 && q == 0 && ok) {
        as_[row] = red[rg][r15][0][0] + red[rg][r15][1][0];
        ad_[row] = red[rg][r15][0][1] + red[rg][r15][1][1];
    }
}

// ==================== K2: agg layer1 (R10-best: preloaded ids, 16-deep) + LN/ELU + gemm2 ====
// Reverted from R11 perm (regressed) and R12 channel-slicing (regressed; FETCH
// invariant falsified the footprint model). id2's sn line (slots 32-47) is now
// only fetched when len>32 (~0.01% of nodes) — saves a 64B line per node.
__global__ __launch_bounds__(512, 4) void k_agg1_gemm2(
    const _Float16* __restrict__ h1, const unsigned short* __restrict__ sn,
    const int* __restrict__ cnt, const float* __restrict__ as1,
    const float* __restrict__ ad1, const float* __restrict__ b1,
    const float* __restrict__ lng, const float* __restrict__ lnb,
    const _Float16* __restrict__ Wt2,
    const float* __restrict__ a_src2, const float* __restrict__ a_dst2,
    _Float16* __restrict__ h2, float* __restrict__ as2, float* __restrict__ ad2,
    int nn)
{
    __shared__ _Float16 yt[32][144];
    __shared__ float red[2][16][4][2];
    int t = blockIdx.x;
    int tid = threadIdx.x;
    int wave = tid >> 6, lane = tid & 63;
    int l4 = lane & 15, q = lane >> 4;
    int qg = wave * 4 + q;                     // 0..31: this quarter's node slot in the tile
    int node = t * 32 + qg;
    bool valid = node < nn;
    const char* hbB = (const char*)h1;
    int qbase = lane & 48;

    int len = 0; float adv = 0.f;
    if (valid) {
        len = cnt[node];
        len = len < STRIDE ? len : STRIDE;
        adv = ad1[node];
    }
    int start = valid ? node * STRIDE : 0;

    // preload edge ids + weights (masked -> id 0, w 0); id0/id1 share a 64B line
    int id0 = sn[start + l4], id1 = sn[start + 16 + l4];
    int id2 = (len > 32) ? sn[start + 32 + l4] : 0;     // 3rd sn line only if needed
    id0 = (l4      < len) ? id0 : 0;
    id1 = (l4 + 16 < len) ? id1 : 0;
    id2 = (l4 + 32 < len) ? id2 : 0;
    float t0 = as1[id0] + adv; t0 = t0 > 0.f ? t0 : NEG_SLOPE * t0;
    float t1 = as1[id1] + adv; t1 = t1 > 0.f ? t1 : NEG_SLOPE * t1;
    float t2 = as1[id2] + adv; t2 = t2 > 0.f ? t2 : NEG_SLOPE * t2;
    float w0 = (l4      < len) ? __expf(fminf(t0, 70.f)) : 0.f;
    float w1 = (l4 + 16 < len) ? __expf(fminf(t1, 70.f)) : 0.f;
    float w2 = (l4 + 32 < len) ? __expf(fminf(t2, 70.f)) : 0.f;
    float wsum = w0 + w1 + w2;

    float acc[8] = {0.f, 0.f, 0.f, 0.f, 0.f, 0.f, 0.f, 0.f};
    agg_half8(hbB, id0, w0, qbase, 0, l4, acc);
    agg_half8(hbB, id0, w0, qbase, 8, l4, acc);
    if (len > 16) {
        agg_half8(hbB, id1, w1, qbase, 0, l4, acc);
        agg_half8(hbB, id1, w1, qbase, 8, l4, acc);
    }
    if (len > 32) {
        agg_half8(hbB, id2, w2, qbase, 0, l4, acc);
        agg_half8(hbB, id2, w2, qbase, 8, l4, acc);
    }
    for (int c = 48; c < len; c += 16) {       // correctness guard; never runs for this data
        int idk = sn[start + c + l4];
        bool a = (c + l4 < len);
        idk = a ? idk : 0;
        float tt = as1[idk] + adv; tt = tt > 0.f ? tt : NEG_SLOPE * tt;
        float wk = a ? __expf(fminf(tt, 70.f)) : 0.f;
        wsum += wk;
        agg_half8(hbB, idk, wk, qbase, 0, l4, acc);
        agg_half8(hbB, idk, wk, qbase, 8, l4, acc);
    }
    float dsum = wsum;
    dsum += __shfl_xor(dsum, 1); dsum += __shfl_xor(dsum, 2);
    dsum += __shfl_xor(dsum, 4); dsum += __shfl_xor(dsum, 8);

    if (valid) {
        float inv = 1.f / dsum;
        float4 b0 = *(const float4*)&b1[l4 * 8];
        float4 bb = *(const float4*)&b1[l4 * 8 + 4];
        float vv[8];
        vv[0] = acc[0] * inv + b0.x; vv[1] = acc[1] * inv + b0.y;
        vv[2] = acc[2] * inv + b0.z; vv[3] = acc[3] * inv + b0.w;
        vv[4] = acc[4] * inv + bb.x; vv[5] = acc[5] * inv + bb.y;
        vv[6] = acc[6] * inv + bb.z; vv[7] = acc[7] * inv + bb.w;

        // LayerNorm across the quarter's 16 lanes
        float s1 = 0.f, s2 = 0.f;
        #pragma unroll
        for (int c = 0; c < 8; ++c) { s1 += vv[c]; s2 += vv[c] * vv[c]; }
        #pragma unroll
        for (int o = 1; o < 16; o <<= 1) {
            s1 += __shfl_xor(s1, o);
            s2 += __shfl_xor(s2, o);
        }
        float mean = s1 * (1.f / 128.f);
        float var  = s2 * (1.f / 128.f) - mean * mean;
        float r = rsqrtf(var + LN_EPS);
        float4 g0 = *(const float4*)&lng[l4 * 8];
        float4 g1 = *(const float4*)&lng[l4 * 8 + 4];
        float4 p0 = *(const float4*)&lnb[l4 * 8];
        float4 p1 = *(const float4*)&lnb[l4 * 8 + 4];
        float gg[8] = {g0.x, g0.y, g0.z, g0.w, g1.x, g1.y, g1.z, g1.w};
        float pp[8] = {p0.x, p0.y, p0.z, p0.w, p1.x, p1.y, p1.z, p1.w};
        f16x8 o;
        #pragma unroll
        for (int c = 0; c < 8; ++c) {
            float u = (vv[c] - mean) * r * gg[c] + pp[c];
            u = u > 0.f ? u : __expf(u) - 1.f;   // ELU
            o[c] = (_Float16)u;
        }
        *(f16x8*)&yt[qg][l4 * 8] = o;
    } else {
        f16x8 z;
        #pragma unroll
        for (int c = 0; c < 8; ++c) z[c] = (_Float16)0.f;
        *(f16x8*)&yt[qg][l4 * 8] = z;
    }
    __syncthreads();

    // ---- gemm2 (K=128) from the LDS tile: 8 waves = 2 rowgroups x 4 col-chunks
    int rg = wave >> 2, cc = wave & 3;
    int r15 = l4;
    int row = t * 32 + rg * 16 + r15;
    bool ok = row < nn;

    f32x4 acc2[2] = {};
    const _Float16* Wp[2];
    #pragma unroll
    for (int s = 0; s < 2; ++s)
        Wp[s] = Wt2 + (size_t)(cc * 32 + s * 16 + r15) * 128 + q * 8;
    const _Float16* Yp = &yt[rg * 16 + r15][q * 8];

    #pragma unroll
    for (int k0 = 0; k0 < 128; k0 += 32) {
        f16x8 wv[2];
        #pragma unroll
        for (int s = 0; s < 2; ++s) wv[s] = *(const f16x8*)(Wp[s] + k0);
        f16x8 xv = *(const f16x8*)(Yp + k0);
        #pragma unroll
        for (int s = 0; s < 2; ++s)
            acc2[s] = __builtin_amdgcn_mfma_f32_16x16x32_f16(wv[s], xv, acc2[s], 0, 0, 0);
    }

    float vs = 0.f, vd = 0.f;
    #pragma unroll
    for (int s = 0; s < 2; ++s) {
        float4 as4 = *(const float4*)&a_src2[cc * 32 + s * 16 + q * 4];
        float4 ad4 = *(const float4*)&a_dst2[cc * 32 + s * 16 + q * 4];
        f32x4 d = acc2[s];
        vs += d[0]*as4.x + d[1]*as4.y + d[2]*as4.z + d[3]*as4.w;
        vd += d[0]*ad4.x + d[1]*ad4.y + d[2]*ad4.z + d[3]*ad4.w;
        if (ok) {
            ushort4 u;
            u.x = __half_as_ushort(__float2half_rn(d[0]));
            u.y = __half_as_ushort(__float2half_rn(d[1]));
            u.z = __half_as_ushort(__float2half_rn(d[2]));
            u.w = __half_as_ushort(__float2half_rn(d[3]));
            *(ushort4*)&h2[(size_t)row * 128 + cc * 32 + s * 16 + q * 4] = u;
        }
    }
    vs += __shfl_xor(vs, 16); vs += __shfl_xor(vs, 32);
    vd += __shfl_xor(vd, 16); vd += __shfl_xor(vd, 32);
    if (q == 0) { red[rg][r15][cc][0] = vs; red[rg][r15][cc][1] = vd; }
    __syncthreads();
    if (cc == 0 && q == 0 && ok) {
        as2[row] = red[rg][r15][0][0] + red[rg][r15][1][0]
                 + red[rg][r15][2][0] + red[rg][r15][3][0];
        ad2[row] = red[rg][r15][0][1] + red[rg][r15][1][1]
                 + red[rg][r15][2][1] + red[rg][r15][3][1];
    }
}

// ==================== K3: agg layer2 (R10-best structure, fp32 out) ====================
__global__ __launch_bounds__(256, 4) void k_agg2(
    const _Float16* __restrict__ hb, const unsigned short* __restrict__ sn,
    const int* __restrict__ cnt, const float* __restrict__ as_,
    const float* __restrict__ ad_, const float* __restrict__ bias,
    float* __restrict__ out, int n_nodes)
{
    int tid = threadIdx.x;
    int wave = tid >> 6, lane = tid & 63;
    int l4 = lane & 15, q = lane >> 4;
    int node = blockIdx.x * 16 + wave * 4 + q;
    if (node >= n_nodes) return;
    int len = cnt[node];
    len = len < STRIDE ? len : STRIDE;
    int start = node * STRIDE;
    int qbase = lane & 48;
    float adv = ad_[node];
    const char* hbB = (const char*)hb;

    int id0 = sn[start + l4], id1 = sn[start + 16 + l4];
    int id2 = (len > 32) ? sn[start + 32 + l4] : 0;     // 3rd sn line only if needed
    id0 = (l4      < len) ? id0 : 0;
    id1 = (l4 + 16 < len) ? id1 : 0;
    id2 = (l4 + 32 < len) ? id2 : 0;
    float t0 = as_[id0] + adv; t0 = t0 > 0.f ? t0 : NEG_SLOPE * t0;
    float t1 = as_[id1] + adv; t1 = t1 > 0.f ? t1 : NEG_SLOPE * t1;
    float t2 = as_[id2] + adv; t2 = t2 > 0.f ? t2 : NEG_SLOPE * t2;
    float w0 = (l4      < len) ? __expf(fminf(t0, 70.f)) : 0.f;
    float w1 = (l4 + 16 < len) ? __expf(fminf(t1, 70.f)) : 0.f;
    float w2 = (l4 + 32 < len) ? __expf(fminf(t2, 70.f)) : 0.f;
    float wsum = w0 + w1 + w2;

    float acc[8] = {0.f, 0.f, 0.f, 0.f, 0.f, 0.f, 0.f, 0.f};
    agg_half8(hbB, id0, w0, qbase, 0, l4, acc);
    agg_half8(hbB, id0, w0, qbase, 8, l4, acc);
    if (len > 16) {
        agg_half8(hbB, id1, w1, qbase, 0, l4, acc);
        agg_half8(hbB, id1, w1, qbase, 8, l4, acc);
    }
    if (len > 32) {
        agg_half8(hbB, id2, w2, qbase, 0, l4, acc);
        agg_half8(hbB, id2, w2, qbase, 8, l4, acc);
    }
    for (int c = 48; c < len; c += 16) {       // correctness guard; never runs for this data
        int idk = sn[start + c + l4];
        bool a = (c + l4 < len);
        idk = a ? idk : 0;
        float tt = as_[idk] + adv; tt = tt > 0.f ? tt : NEG_SLOPE * tt;
        float wk = a ? __expf(fminf(tt, 70.f)) : 0.f;
        wsum += wk;
        agg_half8(hbB, idk, wk, qbase, 0, l4, acc);
        agg_half8(hbB, idk, wk, qbase, 8, l4, acc);
    }
    float dsum = wsum;
    dsum += __shfl_xor(dsum, 1); dsum += __shfl_xor(dsum, 2);
    dsum += __shfl_xor(dsum, 4); dsum += __shfl_xor(dsum, 8);

    float inv = 1.f / dsum;
    float4 b0 = *(const float4*)&bias[l4 * 8];
    float4 b1 = *(const float4*)&bias[l4 * 8 + 4];
    float4 o0 = make_float4(acc[0]*inv + b0.x, acc[1]*inv + b0.y,
                            acc[2]*inv + b0.z, acc[3]*inv + b0.w);
    float4 o1 = make_float4(acc[4]*inv + b1.x, acc[5]*inv + b1.y,
                            acc[6]*inv + b1.z, acc[7]*inv + b1.w);
    *(float4*)(out + (size_t)node * 128 + l4 * 8)     = o0;
    *(float4*)(out + (size_t)node * 128 + l4 * 8 + 4) = o1;
}

// ============================ launch ============================

extern "C" void kernel_launch(void* const* d_in, const int* in_sizes, int n_in,
                              void* d_out, int out_size, void* d_ws, size_t ws_size,
                              hipStream_t stream) {
    const float* x_base   = (const float*)d_in[0];
    const int*   cell_ids = (const int*)d_in[1];
    const int*   eidx     = (const int*)d_in[2];
    const float* cell_emb = (const float*)d_in[3];
    const float* W1     = (const float*)d_in[4];
    const float* a_src1 = (const float*)d_in[5];
    const float* a_dst1 = (const float*)d_in[6];
    const float* b1     = (const float*)d_in[7];
    const float* ln_g   = (const float*)d_in[8];
    const float* ln_b   = (const float*)d_in[9];
    const float* W2     = (const float*)d_in[10];
    const float* a_src2 = (const float*)d_in[11];
    const float* a_dst2 = (const float*)d_in[12];
    const float* b2     = (const float*)d_in[13];

    const int N = in_sizes[0] / 128;
    const int E = in_sizes[2] / 2;

    const int* esrc = eidx;
    const int* edst = eidx + E;

    const int NB   = (N + 1023) >> 10;               // dst-range buckets (1024 nodes each)
    const int NBLK = (E + BS * EPT - 1) / (BS * EPT); // pass-1 blocks (2048 edges each)

    auto align = [](size_t v) { return (v + 255) & ~(size_t)255; };
    char* p = (char*)d_ws;
    int*   cnt    = (int*)p;   p += align((size_t)N * 4);
    unsigned short* sn = (unsigned short*)p; p += align((size_t)N * STRIDE * 2 + 64);
    unsigned int* gb = (unsigned int*)p; p += align((size_t)NB * NBLK * SUBCAP * 4);
    int*   bcnt   = (int*)p;   p += align((size_t)NBLK * NB * 4);
    _Float16* h1  = (_Float16*)p; p += align((size_t)N * 128 * 2);
    _Float16* h2  = (_Float16*)p; p += align((size_t)N * 128 * 2);
    _Float16* Wt1 = (_Float16*)p; p += align((size_t)128 * 160 * 2);
    _Float16* Wt2 = (_Float16*)p; p += align((size_t)128 * 128 * 2);
    float* as1    = (float*)p; p += align((size_t)N * 4);
    float* ad1    = (float*)p; p += align((size_t)N * 4);
    float* as2    = (float*)p; p += align((size_t)N * 4);
    float* ad2    = (float*)p; p += align((size_t)N * 4);
    (void)ws_size; (void)n_in; (void)out_size;

    const int nbG = (N + 31) / 32;                     // 32-row gemm tiles
    const int wblocks = (128 * 160 + 128 * 128 + BS - 1) / BS;

    k_init<<<NBLK + wblocks, BS, 0, stream>>>(
        esrc, edst, gb, bcnt, W1, W2, Wt1, Wt2, E, NB, NBLK);
    k_csr_gemm1<<<NB + nbG, BS, 0, stream>>>(
        gb, bcnt, cnt, sn, x_base, cell_ids, cell_emb, Wt1,
        a_src1, a_dst1, h1, as1, ad1, N, NB, NBLK);
    k_agg1_gemm2<<<nbG, 512, 0, stream>>>(
        h1, sn, cnt, as1, ad1, b1, ln_g, ln_b, Wt2,
        a_src2, a_dst2, h2, as2, ad2, N);
    k_agg2<<<(N + 15) / 16, BS, 0, stream>>>(
        h2, sn, cnt, as2, ad2, b2, (float*)d_out, N);
}